// Round 13
// baseline (1081.090 us; speedup 1.0000x reference)
//
#include <hip/hip_runtime.h>
#include <math.h>

#define N_NODES 100000
#define R_REL   3
#define E_EDGES 1600000
#define HID     64
#define DFLAT   129
#define KTOP    30
#define NC1     16
#define NC2     32
#define KSZ     5
#define NG      64
#define CAP     2048
#define SLOTS   8     // CAP / 256
#define TOUT    11    // K/2 - KS + 1
#define NBLK    391   // ceil(N_NODES/256)
#define NB      391   // coarse buckets (dst>>8)
#define NCHUNK  512   // bin_stage blocks
#define CHSZ    3125  // E_EDGES / NCHUNK (exact)
#define NOUT    (NG * NC2 * TOUT)
#define CAPE    5120  // LDS edge capacity per bucket (mean 4096, sigma ~64)

// Relation-batched kernels: blockIdx.y = workspace slot ry; r_base+ry = real
// relation for INPUT pointers. nslots = 3/2/1 by ws_size (measured: ws fits 2).
// Aliases (lifetime-proven on stream order):
//   staged (dead after bin_scatter3)   == hpre (written by gemm later)
//   enormp == ewp IN PLACE (raw ewp dead after enorm_csr reads it)
//   chunkoff == chist IN PLACE; scatter3 overflow scratch == h1 region

// ---------------- binned permutation build (deterministic chunk order) -------
// R7 lesson: flat counting-sort scatter = ~10x cache-line write amplification.
// R10 lesson: standalone global-memory per-row sort = 170us/381MB writes ->
// sort lives inside the scatter bucket's LDS image; eorig never reaches HBM.
__global__ void __launch_bounds__(256) bin_hist(const int* __restrict__ eidx,
                                                int* __restrict__ chist_all,
                                                int r_base) {
    __shared__ int hist[NB];
    int ry = blockIdx.y;
    const int* dst = eidx + (size_t)(r_base + ry) * 2 * E_EDGES + E_EDGES;
    int* chist = chist_all + (size_t)ry * NB * NCHUNK;
    int t = threadIdx.x, c = blockIdx.x;
    int e0 = c * CHSZ;
    int e1 = e0 + CHSZ; if (e1 > E_EDGES) e1 = E_EDGES;
    for (int j = t; j < NB; j += 256) hist[j] = 0;
    __syncthreads();
    for (int i = e0 + t; i < e1; i += 256)
        atomicAdd(&hist[dst[i] >> 8], 1);
    __syncthreads();
    for (int j = t; j < NB; j += 256) chist[j * NCHUNK + c] = hist[j];
}

// in-place: chunkoff overwrites chist (each element read to LDS before write)
__global__ void __launch_bounds__(512) bin_scan(int* __restrict__ chist_all,
                                                int* __restrict__ btot_all) {
    __shared__ int s[512];
    int ry = blockIdx.y;
    int* chist = chist_all + (size_t)ry * NB * NCHUNK;
    int* btot = btot_all + (size_t)ry * (NB + 1);
    int b = blockIdx.x, t = threadIdx.x;
    int orig = t < NCHUNK ? chist[b * NCHUNK + t] : 0;
    s[t] = orig;
    __syncthreads();
    for (int o = 1; o < 512; o <<= 1) {
        int v = t >= o ? s[t - o] : 0;
        __syncthreads();
        s[t] += v;
        __syncthreads();
    }
    if (t < NCHUNK) chist[b * NCHUNK + t] = s[t] - orig;   // now chunkoff
    if (t == 511) btot[b] = s[511];
}

__global__ void __launch_bounds__(512) bucket_scan(const int* __restrict__ btot_all,
                                                   int* __restrict__ bb_all) {
    __shared__ int s[512];
    int ry = blockIdx.x;            // grid.x = ny here
    const int* btot = btot_all + (size_t)ry * (NB + 1);
    int* bucket_base = bb_all + (size_t)ry * (NB + 1);
    int t = threadIdx.x;
    int orig = t < NB ? btot[t] : 0;
    s[t] = orig;
    __syncthreads();
    for (int o = 1; o < 512; o <<= 1) {
        int v = t >= o ? s[t - o] : 0;
        __syncthreads();
        s[t] += v;
        __syncthreads();
    }
    if (t < NB) bucket_base[t] = s[t] - orig;
    if (t == NB - 1) bucket_base[NB] = s[t];
}

__global__ void __launch_bounds__(256) bin_stage(const int* __restrict__ eidx,
                                                 const float* __restrict__ ew_all,
                                                 const int* __restrict__ chunkoff_all,
                                                 const int* __restrict__ bb_all,
                                                 int4* __restrict__ staged_all,
                                                 int r_base) {
    __shared__ int base[NB];
    __shared__ int lcur[NB];
    int ry = blockIdx.y;
    int rin = r_base + ry;
    const int* src = eidx + (size_t)rin * 2 * E_EDGES;
    const int* dst = src + E_EDGES;
    const float* ew = ew_all + (size_t)rin * E_EDGES;
    const int* chunkoff = chunkoff_all + (size_t)ry * NB * NCHUNK;
    const int* bucket_base = bb_all + (size_t)ry * (NB + 1);
    int4* staged = staged_all + (size_t)ry * E_EDGES;
    int t = threadIdx.x, c = blockIdx.x;
    int e0 = c * CHSZ;
    int e1 = e0 + CHSZ; if (e1 > E_EDGES) e1 = E_EDGES;
    for (int j = t; j < NB; j += 256) {
        base[j] = bucket_base[j] + chunkoff[j * NCHUNK + c];
        lcur[j] = 0;
    }
    __syncthreads();
    for (int i = e0 + t; i < e1; i += 256) {
        int d = dst[i];
        int bin = d >> 8;
        int r = atomicAdd(&lcur[bin], 1);
        staged[(size_t)(base[bin] + r)] = make_int4(d, i, src[i], __float_as_int(ew[i]));
    }
}

// one block per bucket (= 256 consecutive nodes). Scatter bucket records into
// LDS, per-row insertion-sort by eorig IN LDS (bit-identical to global sort),
// dinv from the sorted LDS row (same summation order), coalesced writeback.
// Fallback for bucket > CAPE: global scatter + sort using eo_scratch (h1 region).
__global__ void __launch_bounds__(256) bin_scatter3(const int4* __restrict__ staged_all,
                                                    const int* __restrict__ bb_all,
                                                    int* __restrict__ rowptr_all,
                                                    int* __restrict__ col_all,
                                                    float* __restrict__ ewp_all,
                                                    float* __restrict__ dinv_all,
                                                    int* __restrict__ eo_scratch_all) {
    __shared__ int sc[256];
    __shared__ int cur[256];
    __shared__ int   lcol[CAPE];
    __shared__ float lew[CAPE];
    __shared__ int   leo[CAPE];
    int ry = blockIdx.y;
    const int4* staged = staged_all + (size_t)ry * E_EDGES;
    const int* bucket_base = bb_all + (size_t)ry * (NB + 1);
    int* rowptr = rowptr_all + (size_t)ry * (N_NODES + 1);
    int* col = col_all + (size_t)ry * E_EDGES;
    float* ewp = ewp_all + (size_t)ry * E_EDGES;
    float* dinv = dinv_all + (size_t)ry * N_NODES;
    int b = blockIdx.x, t = threadIdx.x;
    int s0 = bucket_base[b];
    int s1 = bucket_base[b + 1];
    int len = s1 - s0;

    sc[t] = 0;
    __syncthreads();
    for (int i = s0 + t; i < s1; i += 256)
        atomicAdd(&sc[staged[(size_t)i].x & 255], 1);
    __syncthreads();
    int val = sc[t];                 // this thread's row length
    for (int o = 1; o < 256; o <<= 1) {
        int u = t >= o ? sc[t - o] : 0;
        __syncthreads();
        sc[t] += u;
        __syncthreads();
    }
    int lstart = sc[t] - val;        // local (bucket-relative) row start
    int node = (b << 8) + t;
    if (node < N_NODES) rowptr[node] = s0 + lstart;
    if (b == NB - 1 && t == 0) rowptr[N_NODES] = s1;

    if (len <= CAPE) {
        cur[t] = lstart;
        __syncthreads();
        for (int i = s0 + t; i < s1; i += 256) {
            int4 v = staged[(size_t)i];
            int p = atomicAdd(&cur[v.x & 255], 1);
            lcol[p] = v.z;
            lew[p] = __int_as_float(v.w);
            leo[p] = v.y;
        }
        __syncthreads();
        int r0 = lstart, r1 = lstart + val;
        for (int a = r0 + 1; a < r1; ++a) {
            int ke = leo[a]; int kc = lcol[a]; float kw = lew[a];
            int q = a - 1;
            while (q >= r0 && leo[q] > ke) {
                leo[q + 1] = leo[q]; lcol[q + 1] = lcol[q]; lew[q + 1] = lew[q];
                --q;
            }
            leo[q + 1] = ke; lcol[q + 1] = kc; lew[q + 1] = kw;
        }
        float s = 0.0f;
        for (int e = r0; e < r1; ++e) s += lew[e];
        if (node < N_NODES) dinv[node] = 1.0f / sqrtf(s + 1.0f);
        __syncthreads();
        for (int i = t; i < len; i += 256) {
            col[s0 + i] = lcol[i];
            ewp[s0 + i] = lew[i];
        }
    } else {
        int* eo = eo_scratch_all + (size_t)ry * N_NODES * 64;  // h1 slot region
        cur[t] = lstart;
        __syncthreads();
        for (int i = s0 + t; i < s1; i += 256) {
            int4 v = staged[(size_t)i];
            int p = s0 + atomicAdd(&cur[v.x & 255], 1);
            col[p] = v.z;
            ewp[p] = __int_as_float(v.w);
            eo[p] = v.y;
        }
        __syncthreads();
        int r0 = s0 + lstart, r1 = s0 + lstart + val;
        for (int a = r0 + 1; a < r1; ++a) {
            int ke = eo[a]; int kc = col[a]; float kw = ewp[a];
            int q = a - 1;
            while (q >= r0 && eo[q] > ke) {
                eo[q + 1] = eo[q]; col[q + 1] = col[q]; ewp[q + 1] = ewp[q];
                --q;
            }
            eo[q + 1] = ke; col[q + 1] = kc; ewp[q + 1] = kw;
        }
        float s = 0.0f;
        for (int e = r0; e < r1; ++e) s += ewp[e];
        if (node < N_NODES) dinv[node] = 1.0f / sqrtf(s + 1.0f);
    }
}

// per-edge coefficient precompute, IN PLACE: ewp[e] <- dinv[col[e]]*ewp[e]*di.
__global__ void enorm_csr(const int* __restrict__ rowptr_all, const int* __restrict__ col_all,
                          float* __restrict__ ewp_all, const float* __restrict__ dinv_all) {
    int i = blockIdx.x * blockDim.x + threadIdx.x;
    if (i >= N_NODES) return;
    int ry = blockIdx.y;
    const int* rowptr = rowptr_all + (size_t)ry * (N_NODES + 1);
    const int* col = col_all + (size_t)ry * E_EDGES;
    float* ewp = ewp_all + (size_t)ry * E_EDGES;
    const float* dinv = dinv_all + (size_t)ry * N_NODES;
    float di = dinv[i];
    int r1 = rowptr[i + 1];
    for (int e = rowptr[i]; e < r1; ++e)
        ewp[e] = dinv[col[e]] * ewp[e] * di;
}

// ---------------- register-blocked GEMM v5: out[n,64] = X[n,Kd] @ W[Kd,64] ----
// 128 threads/block, 128 rows/block, 8 rows x 8 cols per thread (thread grid
// 16 row-groups x 8 col-groups). Per kk: 4 x ds_read_b128 : 64 FMA -> LDS-pipe
// ratio 1.5x vs v4's 2.25x (3 b128 : 32 FMA). All LDS reads are 8-way
// broadcast + 2-way bank alias (free). Accumulation = one FMA per k in
// ascending k order -> bitwise identical to v4. Register prefetch dbuf kept.
template<int Kd>
__global__ void __launch_bounds__(128) gemm_v5(const float* __restrict__ X,
                                               size_t xstride,
                                               const float* __restrict__ W,
                                               int wstride,
                                               float* __restrict__ out_all,
                                               int r_base) {
    __shared__ float sW[Kd * 64];          // 32/16 KB
    __shared__ float sX[32 * 132];         // 16.9 KB, plane kk: [kk*132 + row]
    const int tid = threadIdx.x;
    const int ry = blockIdx.y;
    const float* Xr = X + (size_t)ry * xstride;
    const float* Wr = W + (size_t)(r_base + ry) * wstride;
    float* out = out_all + (size_t)ry * N_NODES * 64;
    const int g = tid >> 3;                // row group (8 rows), 0..15
    const int c = tid & 7;                 // col group (8 cols)
    const int row0 = blockIdx.x * 128;
    const float4* sW4 = (const float4*)sW;

    // prefetch K-tile 0: 128 rows x 32 k = 1024 float4 / 128 thr = 8 each
    float4 pre[8];
    #pragma unroll
    for (int p = 0; p < 8; ++p) {
        int idx = p * 128 + tid;
        int rowL = idx >> 3, seg = idx & 7;
        int gr = row0 + rowL; if (gr >= N_NODES) gr = N_NODES - 1;
        pre[p] = *(const float4*)(Xr + (size_t)gr * Kd + seg * 4);
    }

    for (int t = tid; t < Kd * 16; t += 128)
        ((float4*)sW)[t] = ((const float4*)Wr)[t];

    float4 acc[8][2];
    #pragma unroll
    for (int j = 0; j < 8; ++j) {
        acc[j][0] = make_float4(0.f, 0.f, 0.f, 0.f);
        acc[j][1] = make_float4(0.f, 0.f, 0.f, 0.f);
    }

    for (int k0 = 0; k0 < Kd; k0 += 32) {
        #pragma unroll
        for (int p = 0; p < 8; ++p) {
            int idx = p * 128 + tid;
            int rowL = idx >> 3, seg = idx & 7;
            sX[(seg * 4 + 0) * 132 + rowL] = pre[p].x;
            sX[(seg * 4 + 1) * 132 + rowL] = pre[p].y;
            sX[(seg * 4 + 2) * 132 + rowL] = pre[p].z;
            sX[(seg * 4 + 3) * 132 + rowL] = pre[p].w;
        }
        __syncthreads();                   // tile visible (sW too on first iter)

        if (k0 + 32 < Kd) {
            #pragma unroll
            for (int p = 0; p < 8; ++p) {
                int idx = p * 128 + tid;
                int rowL = idx >> 3, seg = idx & 7;
                int gr = row0 + rowL; if (gr >= N_NODES) gr = N_NODES - 1;
                pre[p] = *(const float4*)(Xr + (size_t)gr * Kd + k0 + 32 + seg * 4);
            }
        }

        #pragma unroll
        for (int kk = 0; kk < 32; ++kk) {
            float4 xa = *(const float4*)(sX + kk * 132 + 8 * g);
            float4 xb = *(const float4*)(sX + kk * 132 + 8 * g + 4);
            float4 wa = sW4[(k0 + kk) * 16 + 2 * c];
            float4 wb = sW4[(k0 + kk) * 16 + 2 * c + 1];
            #pragma unroll
            for (int j = 0; j < 8; ++j) {
                float xj = (j == 0) ? xa.x : (j == 1) ? xa.y : (j == 2) ? xa.z :
                           (j == 3) ? xa.w : (j == 4) ? xb.x : (j == 5) ? xb.y :
                           (j == 6) ? xb.z : xb.w;
                acc[j][0].x += xj * wa.x; acc[j][0].y += xj * wa.y;
                acc[j][0].z += xj * wa.z; acc[j][0].w += xj * wa.w;
                acc[j][1].x += xj * wb.x; acc[j][1].y += xj * wb.y;
                acc[j][1].z += xj * wb.z; acc[j][1].w += xj * wb.w;
            }
        }
        __syncthreads();
    }

    #pragma unroll
    for (int j = 0; j < 8; ++j) {
        int rr = row0 + 8 * g + j;
        if (rr < N_NODES) {
            float4* op = (float4*)(out + (size_t)rr * 64 + 8 * c);
            op[0] = acc[j][0];
            op[1] = acc[j][1];
        }
    }
}

// -------- fused CSR aggregation (64 feats): one wave per dst row, lane = feat ----
// R1-optimal gather structure; pinned at the scattered-gather ceiling
// (~3.6TB/s TCC; 45% HBM + 47% VALU + 79% occ; 4 structural variants +-8%).
template<int GEMV>
__global__ void __launch_bounds__(256) agg64_fused(const int* __restrict__ rowptr_all,
                                                   const int* __restrict__ col_all,
                                                   const float* __restrict__ enormp_all,
                                                   const float* __restrict__ hpre_all,
                                                   const float* __restrict__ dinv_all,
                                                   const float* __restrict__ bias_all,
                                                   const float* __restrict__ w2_all,
                                                   float* __restrict__ hout_all,
                                                   float* __restrict__ hpre3_all,
                                                   int r_base) {
    int gid = blockIdx.x * 256 + threadIdx.x;
    int row = gid >> 6;
    int lane = gid & 63;
    if (row >= N_NODES) return;
    int ry = blockIdx.y;
    int rin = r_base + ry;
    const int* rowptr = rowptr_all + (size_t)ry * (N_NODES + 1);
    const int* col = col_all + (size_t)ry * E_EDGES;
    const float* enormp = enormp_all + (size_t)ry * E_EDGES;
    const float* hpre = hpre_all + (size_t)ry * N_NODES * 64;
    const float* bias = bias_all + (size_t)rin * 64;
    int r0 = rowptr[row], r1 = rowptr[row + 1];
    float acc = 0.0f;
    for (int base = r0; base < r1; base += 64) {
        int e = base + lane;
        int cv = 0; float ev = 0.0f;
        if (e < r1) { cv = col[e]; ev = enormp[e]; }
        int m = r1 - base; if (m > 64) m = 64;
        int j = 0;
        for (; j + 8 <= m; j += 8) {
            int   s0 = __shfl(cv, j, 64),     s1 = __shfl(cv, j + 1, 64);
            int   s2 = __shfl(cv, j + 2, 64), s3 = __shfl(cv, j + 3, 64);
            int   s4 = __shfl(cv, j + 4, 64), s5 = __shfl(cv, j + 5, 64);
            int   s6 = __shfl(cv, j + 6, 64), s7 = __shfl(cv, j + 7, 64);
            float c0 = __shfl(ev, j, 64),     c1 = __shfl(ev, j + 1, 64);
            float c2 = __shfl(ev, j + 2, 64), c3 = __shfl(ev, j + 3, 64);
            float c4 = __shfl(ev, j + 4, 64), c5 = __shfl(ev, j + 5, 64);
            float c6 = __shfl(ev, j + 6, 64), c7 = __shfl(ev, j + 7, 64);
            float v0 = hpre[(size_t)s0 * 64 + lane];
            float v1 = hpre[(size_t)s1 * 64 + lane];
            float v2 = hpre[(size_t)s2 * 64 + lane];
            float v3 = hpre[(size_t)s3 * 64 + lane];
            float v4 = hpre[(size_t)s4 * 64 + lane];
            float v5 = hpre[(size_t)s5 * 64 + lane];
            float v6 = hpre[(size_t)s6 * 64 + lane];
            float v7 = hpre[(size_t)s7 * 64 + lane];
            acc += c0 * v0; acc += c1 * v1; acc += c2 * v2; acc += c3 * v3;
            acc += c4 * v4; acc += c5 * v5; acc += c6 * v6; acc += c7 * v7;
        }
        for (; j + 4 <= m; j += 4) {
            int   s0 = __shfl(cv, j, 64),     s1 = __shfl(cv, j + 1, 64);
            int   s2 = __shfl(cv, j + 2, 64), s3 = __shfl(cv, j + 3, 64);
            float c0 = __shfl(ev, j, 64),     c1 = __shfl(ev, j + 1, 64);
            float c2 = __shfl(ev, j + 2, 64), c3 = __shfl(ev, j + 3, 64);
            float v0 = hpre[(size_t)s0 * 64 + lane];
            float v1 = hpre[(size_t)s1 * 64 + lane];
            float v2 = hpre[(size_t)s2 * 64 + lane];
            float v3 = hpre[(size_t)s3 * 64 + lane];
            acc += c0 * v0; acc += c1 * v1; acc += c2 * v2; acc += c3 * v3;
        }
        for (; j < m; ++j) {
            int s = __shfl(cv, j, 64);
            float coef = __shfl(ev, j, 64);
            acc += coef * hpre[(size_t)s * 64 + lane];
        }
    }
    float dv = dinv_all[(size_t)ry * N_NODES + row];
    float val = tanhf(acc + dv * dv * hpre[(size_t)row * 64 + lane] + bias[lane]);
    hout_all[(size_t)ry * N_NODES * 64 + (size_t)row * 64 + lane] = val;
    if (GEMV) {
        float v = val * w2_all[(size_t)rin * 64 + lane];
        #pragma unroll
        for (int off = 32; off > 0; off >>= 1) v += __shfl_down(v, off, 64);
        if (lane == 0) hpre3_all[(size_t)ry * N_NODES + row] = v;
    }
}

// -------- fused CSR aggregation (1 feat): one thread per dst row --------
__global__ void agg1_fused(const int* __restrict__ rowptr_all, const int* __restrict__ col_all,
                           const float* __restrict__ enormp_all, const float* __restrict__ hpre3_all,
                           const float* __restrict__ dinv_all, const float* __restrict__ b2_all,
                           float* __restrict__ h3_all, int r_base) {
    int i = blockIdx.x * blockDim.x + threadIdx.x;
    if (i >= N_NODES) return;
    int ry = blockIdx.y;
    const int* rowptr = rowptr_all + (size_t)ry * (N_NODES + 1);
    const int* col = col_all + (size_t)ry * E_EDGES;
    const float* enormp = enormp_all + (size_t)ry * E_EDGES;
    const float* hpre3 = hpre3_all + (size_t)ry * N_NODES;
    float acc = 0.0f;
    int r1 = rowptr[i + 1];
    for (int e = rowptr[i]; e < r1; ++e) acc += enormp[e] * hpre3[col[e]];
    float dv = dinv_all[(size_t)ry * N_NODES + i];
    h3_all[(size_t)ry * N_NODES + i] =
        tanhf(acc + dv * dv * hpre3[i] + b2_all[r_base + ry]);
}

// ---------------- group compaction: deterministic counting sort ----------------
__global__ void __launch_bounds__(256) grp_hist(const int* __restrict__ group,
                                                int* __restrict__ bcnt, int n) {
    __shared__ int lh[NG];
    int b = blockIdx.x, t = threadIdx.x;
    if (t < NG) lh[t] = 0;
    __syncthreads();
    int i = b * 256 + t;
    if (i < n) atomicAdd(&lh[group[i]], 1);
    __syncthreads();
    if (t < NG) bcnt[t * NBLK + b] = lh[t];
}

__global__ void __launch_bounds__(512) grp_scan(const int* __restrict__ bcnt,
                                                int* __restrict__ boff,
                                                int* __restrict__ cnt) {
    __shared__ int s[512];
    int g = blockIdx.x, t = threadIdx.x;
    int orig = t < NBLK ? bcnt[g * NBLK + t] : 0;
    s[t] = orig;
    __syncthreads();
    for (int o = 1; o < 512; o <<= 1) {
        int v = t >= o ? s[t - o] : 0;
        __syncthreads();
        s[t] += v;
        __syncthreads();
    }
    if (t < NBLK) boff[g * NBLK + t] = s[t] - orig;
    if (t == 511) cnt[g] = s[NBLK - 1] > CAP ? CAP : s[NBLK - 1];
}

__global__ void __launch_bounds__(256) grp_fill(const int* __restrict__ group,
                                                const int* __restrict__ boff,
                                                int* __restrict__ lists, int n) {
    __shared__ int lcur[NG];
    int b = blockIdx.x, t = threadIdx.x;
    if (t < NG) lcur[t] = 0;
    __syncthreads();
    int i = b * 256 + t;
    if (i < n) {
        int g = group[i];
        int p = atomicAdd(&lcur[g], 1);
        int pos = boff[g * NBLK + b] + p;
        if (pos < CAP) lists[g * CAP + pos] = i;
    }
}

// ---------------- fused per-group top-K + sort-pool + conv1 + maxpool + conv2 ----
__device__ __forceinline__ unsigned int fkey(float v) {
    unsigned int b = __float_as_uint(v);
    return (b & 0x80000000u) ? ~b : (b | 0x80000000u);
}

__global__ void __launch_bounds__(256) topk_pool(const int* __restrict__ cnt,
                                                 const int* __restrict__ lists,
                                                 const float* __restrict__ h1_all,
                                                 const float* __restrict__ h2_all,
                                                 const float* __restrict__ h3_all,
                                                 const float* __restrict__ c1w,
                                                 const float* __restrict__ c1b,
                                                 const float* __restrict__ c2w,
                                                 const float* __restrict__ c2b,
                                                 float* __restrict__ out3,
                                                 int r_base) {
    __shared__ unsigned long long wmax[4];
    __shared__ unsigned long long winner;
    __shared__ int s_top[KTOP];
    __shared__ float sfeat[KTOP * DFLAT];
    __shared__ float sy[NC1 * KTOP];
    __shared__ float sm[NC1 * (KTOP / 2)];
    int g = blockIdx.x;
    int ry = blockIdx.y;
    const float* h1 = h1_all + (size_t)ry * N_NODES * 64;
    const float* h2 = h2_all + (size_t)ry * N_NODES * 64;
    const float* h3 = h3_all + (size_t)ry * N_NODES;
    float* o = out3 + (size_t)(r_base + ry) * NOUT;
    int tid = threadIdx.x;
    int lane = tid & 63, wid = tid >> 6;
    int c = cnt[g];
    if (c > CAP) c = CAP;

    unsigned long long key[SLOTS];
    #pragma unroll
    for (int s = 0; s < SLOTS; ++s) {
        int e = s * 256 + tid;
        if (e < c) {
            int node = lists[g * CAP + e];
            key[s] = ((unsigned long long)fkey(h3[node]) << 32) | (unsigned int)(~node);
        } else {
            key[s] = 0ull;
        }
    }

    for (int k = 0; k < KTOP; ++k) {
        unsigned long long best = 0ull;
        #pragma unroll
        for (int s = 0; s < SLOTS; ++s) best = key[s] > best ? key[s] : best;
        #pragma unroll
        for (int off = 32; off > 0; off >>= 1) {
            unsigned long long oo = __shfl_down(best, off, 64);
            best = oo > best ? oo : best;
        }
        if (lane == 0) wmax[wid] = best;
        __syncthreads();
        if (tid == 0) {
            unsigned long long b = wmax[0];
            for (int w = 1; w < 4; ++w) b = wmax[w] > b ? wmax[w] : b;
            winner = b;
            s_top[k] = ~(int)(unsigned int)b;
        }
        __syncthreads();
        unsigned long long w = winner;
        #pragma unroll
        for (int s = 0; s < SLOTS; ++s) if (key[s] == w) key[s] = 0ull;
        __syncthreads();
    }

    for (int t = tid; t < KTOP * DFLAT; t += blockDim.x) {
        int k = t / DFLAT, d = t - k * DFLAT;
        int node = s_top[k];
        float v;
        if (d < 64)        v = h1[(size_t)node * 64 + d];
        else if (d < 128)  v = h2[(size_t)node * 64 + (d - 64)];
        else               v = h3[node];
        sfeat[t] = v;
    }
    __syncthreads();

    for (int t = tid; t < NC1 * KTOP; t += blockDim.x) {
        int cc = t / KTOP, k = t - cc * KTOP;
        float acc = c1b[cc];
        const float* w = c1w + cc * DFLAT;
        const float* f = sfeat + k * DFLAT;
        for (int d = 0; d < DFLAT; ++d) acc += f[d] * w[d];
        sy[cc * KTOP + k] = fmaxf(acc, 0.0f);
    }
    __syncthreads();

    for (int t = tid; t < NC1 * (KTOP / 2); t += blockDim.x) {
        int cc = t / (KTOP / 2), j = t - cc * (KTOP / 2);
        sm[t] = fmaxf(sy[cc * KTOP + 2 * j], sy[cc * KTOP + 2 * j + 1]);
    }
    __syncthreads();

    for (int t = tid; t < NC2 * TOUT; t += blockDim.x) {
        int c2 = t / TOUT, tt = t - c2 * TOUT;
        float acc = c2b[c2];
        for (int c1i = 0; c1i < NC1; ++c1i) {
            const float* w = c2w + (c2 * NC1 + c1i) * KSZ;
            const float* m = sm + c1i * (KTOP / 2) + tt;
            for (int s = 0; s < KSZ; ++s) acc += m[s] * w[s];
        }
        o[g * NC2 * TOUT + t] = fmaxf(acc, 0.0f);
    }
}

// final sum over relations in fixed order r0,r1,r2 -> bitwise identical to the
// old sequential "+=" accumulation ((0+v0)+v1)+v2.
__global__ void reduce_out(const float* __restrict__ out3, float* __restrict__ out, int n) {
    int i = blockIdx.x * blockDim.x + threadIdx.x;
    if (i >= n) return;
    float s = 0.0f;
    s += out3[i];
    s += out3[(size_t)n + i];
    s += out3[(size_t)2 * n + i];
    out[i] = s;
}

// ---------------- host ----------------
extern "C" void kernel_launch(void* const* d_in, const int* in_sizes, int n_in,
                              void* d_out, int out_size, void* d_ws, size_t ws_size,
                              hipStream_t stream) {
    const float* x       = (const float*)d_in[0];
    const int*   eidx    = (const int*)d_in[1];    // [R,2,E]
    const float* ew      = (const float*)d_in[2];  // [R,E]
    const int*   group   = (const int*)d_in[3];    // [N]
    const float* W0      = (const float*)d_in[4];  // [R,128,64]
    const float* b0      = (const float*)d_in[5];
    const float* W1      = (const float*)d_in[6];  // [R,64,64]
    const float* b1      = (const float*)d_in[7];
    const float* W2      = (const float*)d_in[8];  // [R,64,1]
    const float* b2      = (const float*)d_in[9];
    const float* c1w     = (const float*)d_in[10];
    const float* c1b     = (const float*)d_in[11];
    const float* c2w     = (const float*)d_in[12];
    const float* c2b     = (const float*)d_in[13];
    float* out = (float*)d_out;

    char* ws = (char*)d_ws;

    float *dinv, *ewp, *hpre, *h1, *h2, *hpre3, *h3, *out3;
    int *rowptr, *col, *cnt, *lists, *bcnt, *boff, *chist, *btot, *bb;
    int4* staged;

    size_t off = 0;
    auto layout = [&](char* base, int ns) -> size_t {
        off = 0;
        auto A = [&](size_t bytes) -> char* {
            char* p = base + off;
            off = (off + bytes + 255) & ~(size_t)255;
            return p;
        };
        dinv    = (float*)A((size_t)ns * N_NODES * 4);
        rowptr  = (int*)  A((size_t)ns * (N_NODES + 1) * 4);
        col     = (int*)  A((size_t)ns * E_EDGES * 4);
        ewp     = (float*)A((size_t)ns * E_EDGES * 4);   // becomes enormp in place
        staged  = (int4*) A((size_t)ns * E_EDGES * 16);  // aliases hpre
        hpre    = (float*)staged;
        h1      = (float*)A((size_t)ns * N_NODES * 64 * 4);  // also scatter3 fallback scratch
        h2      = (float*)A((size_t)ns * N_NODES * 64 * 4);
        hpre3   = (float*)A((size_t)ns * N_NODES * 4);
        h3      = (float*)A((size_t)ns * N_NODES * 4);
        out3    = (float*)A((size_t)3 * NOUT * 4);       // always 3 (indexed by real r)
        cnt     = (int*)  A((size_t)NG * 4);
        lists   = (int*)  A((size_t)NG * CAP * 4);
        bcnt    = (int*)  A((size_t)NG * NBLK * 4);
        boff    = (int*)  A((size_t)NG * NBLK * 4);
        chist   = (int*)  A((size_t)ns * NB * NCHUNK * 4);  // scanned in place -> chunkoff
        btot    = (int*)  A((size_t)ns * (NB + 1) * 4);
        bb      = (int*)  A((size_t)ns * (NB + 1) * 4);
        return off;
    };

    int nslots = 3;
    size_t need = layout(ws, 3);
    if (need > ws_size) { nslots = 2; need = layout(ws, 2); }
    if (need > ws_size) { nslots = 1; need = layout(ws, 1); }

    const int B  = 256;
    const int gN = (N_NODES + B - 1) / B;          // 391
    const int gW = (N_NODES * 64 + B - 1) / B;     // 25000
    const int gG = (N_NODES + 127) / 128;          // 782
    const dim3 blk(B);

    // group compaction: relation-independent, once per launch
    grp_hist<<<NBLK, B, 0, stream>>>(group, bcnt, N_NODES);
    grp_scan<<<NG, 512, 0, stream>>>(bcnt, boff, cnt);
    grp_fill<<<NBLK, B, 0, stream>>>(group, boff, lists, N_NODES);

    for (int r0 = 0; r0 < R_REL; r0 += nslots) {
        int ny = R_REL - r0; if (ny > nslots) ny = nslots;

        // ---- binned permutation CSR build (sort + dinv fused into scatter3) ----
        bin_hist   <<<dim3(NCHUNK, ny), blk, 0, stream>>>(eidx, chist, r0);
        bin_scan   <<<dim3(NB, ny), dim3(512), 0, stream>>>(chist, btot);
        bucket_scan<<<dim3(ny), dim3(512), 0, stream>>>(btot, bb);
        bin_stage  <<<dim3(NCHUNK, ny), blk, 0, stream>>>(eidx, ew, chist, bb,
                                                          staged, r0);
        bin_scatter3<<<dim3(NB, ny), blk, 0, stream>>>(staged, bb, rowptr,
                                                       col, ewp, dinv, (int*)h1);
        enorm_csr  <<<dim3(gN, ny), blk, 0, stream>>>(rowptr, col, ewp, dinv);

        // layer 1 (hpre overwrites the now-dead staged)
        gemm_v5<128><<<dim3(gG, ny), dim3(128), 0, stream>>>(x, 0, W0, 128 * 64,
                                                             hpre, r0);
        agg64_fused<0><<<dim3(gW, ny), blk, 0, stream>>>(rowptr, col, ewp, hpre,
                                                         dinv, b0, nullptr, h1,
                                                         nullptr, r0);
        // layer 2 (+ fused gemv -> hpre3)
        gemm_v5<64><<<dim3(gG, ny), dim3(128), 0, stream>>>(h1, (size_t)N_NODES * 64,
                                                            W1, 64 * 64, hpre, r0);
        agg64_fused<1><<<dim3(gW, ny), blk, 0, stream>>>(rowptr, col, ewp, hpre,
                                                         dinv, b1, W2, h2, hpre3, r0);
        // layer 3
        agg1_fused<<<dim3(gN, ny), blk, 0, stream>>>(rowptr, col, ewp, hpre3,
                                                     dinv, b2, h3, r0);
        // fused sort pooling + convs (writes out3 slice for real relation r0+ry)
        topk_pool<<<dim3(NG, ny), blk, 0, stream>>>(cnt, lists, h1, h2, h3,
                                                    c1w, c1b, c2w, c2b, out3, r0);
    }

    reduce_out<<<(NOUT + B - 1) / B, B, 0, stream>>>(out3, out, NOUT);
}

// Round 14
// 1016.042 us; speedup vs baseline: 1.0640x; 1.0640x over previous
//
#include <hip/hip_runtime.h>
#include <math.h>

#define N_NODES 100000
#define R_REL   3
#define E_EDGES 1600000
#define HID     64
#define DFLAT   129
#define KTOP    30
#define NC1     16
#define NC2     32
#define KSZ     5
#define NG      64
#define CAP     2048
#define SLOTS   8     // CAP / 256
#define TOUT    11    // K/2 - KS + 1
#define NBLK    391   // ceil(N_NODES/256)
#define NB      391   // coarse buckets (dst>>8)
#define NCHUNK  512   // bin_stage blocks
#define CHSZ    3125  // E_EDGES / NCHUNK (exact)
#define NOUT    (NG * NC2 * TOUT)
#define CAPE    5120  // LDS edge capacity per bucket (mean 4096, sigma ~64)

// Relation-batched kernels: blockIdx.y = workspace slot ry; r_base+ry = real
// relation for INPUT pointers. nslots = 3/2/1 by ws_size (measured: ws fits 2).
// Aliases (lifetime-proven on stream order):
//   staged (dead after bin_scatter3)   == hpre (written by gemm later)
//   enormp == ewp IN PLACE (raw ewp dead after enorm_csr reads it)
//   chunkoff == chist IN PLACE; scatter3 overflow scratch == h1 region
// GEMM history: v4 (256thr, 4x8 tile, reg-prefetch) is the measured optimum.
// v5 (128thr, 8x8 tile, better LDS ratio) REGRESSED +16us/dispatch: 49KB LDS
// at 128 thr -> 1.5 waves/SIMD, latency-starved (same failure mode as R0).

// ---------------- binned permutation build (deterministic chunk order) -------
// R7 lesson: flat counting-sort scatter = ~10x cache-line write amplification.
// R10 lesson: standalone global-memory per-row sort = 170us/381MB writes ->
// sort lives inside the scatter bucket's LDS image; eorig never reaches HBM.
__global__ void __launch_bounds__(256) bin_hist(const int* __restrict__ eidx,
                                                int* __restrict__ chist_all,
                                                int r_base) {
    __shared__ int hist[NB];
    int ry = blockIdx.y;
    const int* dst = eidx + (size_t)(r_base + ry) * 2 * E_EDGES + E_EDGES;
    int* chist = chist_all + (size_t)ry * NB * NCHUNK;
    int t = threadIdx.x, c = blockIdx.x;
    int e0 = c * CHSZ;
    int e1 = e0 + CHSZ; if (e1 > E_EDGES) e1 = E_EDGES;
    for (int j = t; j < NB; j += 256) hist[j] = 0;
    __syncthreads();
    for (int i = e0 + t; i < e1; i += 256)
        atomicAdd(&hist[dst[i] >> 8], 1);
    __syncthreads();
    for (int j = t; j < NB; j += 256) chist[j * NCHUNK + c] = hist[j];
}

// in-place: chunkoff overwrites chist (each element read to LDS before write)
__global__ void __launch_bounds__(512) bin_scan(int* __restrict__ chist_all,
                                                int* __restrict__ btot_all) {
    __shared__ int s[512];
    int ry = blockIdx.y;
    int* chist = chist_all + (size_t)ry * NB * NCHUNK;
    int* btot = btot_all + (size_t)ry * (NB + 1);
    int b = blockIdx.x, t = threadIdx.x;
    int orig = t < NCHUNK ? chist[b * NCHUNK + t] : 0;
    s[t] = orig;
    __syncthreads();
    for (int o = 1; o < 512; o <<= 1) {
        int v = t >= o ? s[t - o] : 0;
        __syncthreads();
        s[t] += v;
        __syncthreads();
    }
    if (t < NCHUNK) chist[b * NCHUNK + t] = s[t] - orig;   // now chunkoff
    if (t == 511) btot[b] = s[511];
}

__global__ void __launch_bounds__(512) bucket_scan(const int* __restrict__ btot_all,
                                                   int* __restrict__ bb_all) {
    __shared__ int s[512];
    int ry = blockIdx.x;            // grid.x = ny here
    const int* btot = btot_all + (size_t)ry * (NB + 1);
    int* bucket_base = bb_all + (size_t)ry * (NB + 1);
    int t = threadIdx.x;
    int orig = t < NB ? btot[t] : 0;
    s[t] = orig;
    __syncthreads();
    for (int o = 1; o < 512; o <<= 1) {
        int v = t >= o ? s[t - o] : 0;
        __syncthreads();
        s[t] += v;
        __syncthreads();
    }
    if (t < NB) bucket_base[t] = s[t] - orig;
    if (t == NB - 1) bucket_base[NB] = s[t];
}

__global__ void __launch_bounds__(256) bin_stage(const int* __restrict__ eidx,
                                                 const float* __restrict__ ew_all,
                                                 const int* __restrict__ chunkoff_all,
                                                 const int* __restrict__ bb_all,
                                                 int4* __restrict__ staged_all,
                                                 int r_base) {
    __shared__ int base[NB];
    __shared__ int lcur[NB];
    int ry = blockIdx.y;
    int rin = r_base + ry;
    const int* src = eidx + (size_t)rin * 2 * E_EDGES;
    const int* dst = src + E_EDGES;
    const float* ew = ew_all + (size_t)rin * E_EDGES;
    const int* chunkoff = chunkoff_all + (size_t)ry * NB * NCHUNK;
    const int* bucket_base = bb_all + (size_t)ry * (NB + 1);
    int4* staged = staged_all + (size_t)ry * E_EDGES;
    int t = threadIdx.x, c = blockIdx.x;
    int e0 = c * CHSZ;
    int e1 = e0 + CHSZ; if (e1 > E_EDGES) e1 = E_EDGES;
    for (int j = t; j < NB; j += 256) {
        base[j] = bucket_base[j] + chunkoff[j * NCHUNK + c];
        lcur[j] = 0;
    }
    __syncthreads();
    for (int i = e0 + t; i < e1; i += 256) {
        int d = dst[i];
        int bin = d >> 8;
        int r = atomicAdd(&lcur[bin], 1);
        staged[(size_t)(base[bin] + r)] = make_int4(d, i, src[i], __float_as_int(ew[i]));
    }
}

// one block per bucket (= 256 consecutive nodes). Scatter bucket records into
// LDS, per-row insertion-sort by eorig IN LDS (bit-identical to global sort),
// dinv from the sorted LDS row (same summation order), coalesced writeback.
// Fallback for bucket > CAPE: global scatter + sort using eo_scratch (h1 region).
__global__ void __launch_bounds__(256) bin_scatter3(const int4* __restrict__ staged_all,
                                                    const int* __restrict__ bb_all,
                                                    int* __restrict__ rowptr_all,
                                                    int* __restrict__ col_all,
                                                    float* __restrict__ ewp_all,
                                                    float* __restrict__ dinv_all,
                                                    int* __restrict__ eo_scratch_all) {
    __shared__ int sc[256];
    __shared__ int cur[256];
    __shared__ int   lcol[CAPE];
    __shared__ float lew[CAPE];
    __shared__ int   leo[CAPE];
    int ry = blockIdx.y;
    const int4* staged = staged_all + (size_t)ry * E_EDGES;
    const int* bucket_base = bb_all + (size_t)ry * (NB + 1);
    int* rowptr = rowptr_all + (size_t)ry * (N_NODES + 1);
    int* col = col_all + (size_t)ry * E_EDGES;
    float* ewp = ewp_all + (size_t)ry * E_EDGES;
    float* dinv = dinv_all + (size_t)ry * N_NODES;
    int b = blockIdx.x, t = threadIdx.x;
    int s0 = bucket_base[b];
    int s1 = bucket_base[b + 1];
    int len = s1 - s0;

    sc[t] = 0;
    __syncthreads();
    for (int i = s0 + t; i < s1; i += 256)
        atomicAdd(&sc[staged[(size_t)i].x & 255], 1);
    __syncthreads();
    int val = sc[t];                 // this thread's row length
    for (int o = 1; o < 256; o <<= 1) {
        int u = t >= o ? sc[t - o] : 0;
        __syncthreads();
        sc[t] += u;
        __syncthreads();
    }
    int lstart = sc[t] - val;        // local (bucket-relative) row start
    int node = (b << 8) + t;
    if (node < N_NODES) rowptr[node] = s0 + lstart;
    if (b == NB - 1 && t == 0) rowptr[N_NODES] = s1;

    if (len <= CAPE) {
        cur[t] = lstart;
        __syncthreads();
        for (int i = s0 + t; i < s1; i += 256) {
            int4 v = staged[(size_t)i];
            int p = atomicAdd(&cur[v.x & 255], 1);
            lcol[p] = v.z;
            lew[p] = __int_as_float(v.w);
            leo[p] = v.y;
        }
        __syncthreads();
        int r0 = lstart, r1 = lstart + val;
        for (int a = r0 + 1; a < r1; ++a) {
            int ke = leo[a]; int kc = lcol[a]; float kw = lew[a];
            int q = a - 1;
            while (q >= r0 && leo[q] > ke) {
                leo[q + 1] = leo[q]; lcol[q + 1] = lcol[q]; lew[q + 1] = lew[q];
                --q;
            }
            leo[q + 1] = ke; lcol[q + 1] = kc; lew[q + 1] = kw;
        }
        float s = 0.0f;
        for (int e = r0; e < r1; ++e) s += lew[e];
        if (node < N_NODES) dinv[node] = 1.0f / sqrtf(s + 1.0f);
        __syncthreads();
        for (int i = t; i < len; i += 256) {
            col[s0 + i] = lcol[i];
            ewp[s0 + i] = lew[i];
        }
    } else {
        int* eo = eo_scratch_all + (size_t)ry * N_NODES * 64;  // h1 slot region
        cur[t] = lstart;
        __syncthreads();
        for (int i = s0 + t; i < s1; i += 256) {
            int4 v = staged[(size_t)i];
            int p = s0 + atomicAdd(&cur[v.x & 255], 1);
            col[p] = v.z;
            ewp[p] = __int_as_float(v.w);
            eo[p] = v.y;
        }
        __syncthreads();
        int r0 = s0 + lstart, r1 = s0 + lstart + val;
        for (int a = r0 + 1; a < r1; ++a) {
            int ke = eo[a]; int kc = col[a]; float kw = ewp[a];
            int q = a - 1;
            while (q >= r0 && eo[q] > ke) {
                eo[q + 1] = eo[q]; col[q + 1] = col[q]; ewp[q + 1] = ewp[q];
                --q;
            }
            eo[q + 1] = ke; col[q + 1] = kc; ewp[q + 1] = kw;
        }
        float s = 0.0f;
        for (int e = r0; e < r1; ++e) s += ewp[e];
        if (node < N_NODES) dinv[node] = 1.0f / sqrtf(s + 1.0f);
    }
}

// per-edge coefficient precompute, IN PLACE: ewp[e] <- dinv[col[e]]*ewp[e]*di.
__global__ void enorm_csr(const int* __restrict__ rowptr_all, const int* __restrict__ col_all,
                          float* __restrict__ ewp_all, const float* __restrict__ dinv_all) {
    int i = blockIdx.x * blockDim.x + threadIdx.x;
    if (i >= N_NODES) return;
    int ry = blockIdx.y;
    const int* rowptr = rowptr_all + (size_t)ry * (N_NODES + 1);
    const int* col = col_all + (size_t)ry * E_EDGES;
    float* ewp = ewp_all + (size_t)ry * E_EDGES;
    const float* dinv = dinv_all + (size_t)ry * N_NODES;
    float di = dinv[i];
    int r1 = rowptr[i + 1];
    for (int e = rowptr[i]; e < r1; ++e)
        ewp[e] = dinv[col[e]] * ewp[e] * di;
}

// ---------------- register-blocked GEMM v4: out[n,64] = X[n,Kd] @ W[Kd,64] ----
// 256 threads/block, 128 rows/block, 4x8 micro-tile (32 row-groups x 8 col-
// groups), 3 ds_read_b128 : 32 FMA, register-prefetch double-buffer.
// Measured optimum (R12: total 1017us); v5's fatter tile regressed (occupancy).
template<int Kd>
__global__ void __launch_bounds__(256) gemm_v4(const float* __restrict__ X,
                                               size_t xstride,
                                               const float* __restrict__ W,
                                               int wstride,
                                               float* __restrict__ out_all,
                                               int r_base) {
    __shared__ float sW[Kd * 64];
    __shared__ float sX[32 * 132];
    const int tid = threadIdx.x;
    const int ry = blockIdx.y;
    const float* Xr = X + (size_t)ry * xstride;
    const float* Wr = W + (size_t)(r_base + ry) * wstride;
    float* out = out_all + (size_t)ry * N_NODES * 64;
    const int g = tid >> 3;
    const int c = tid & 7;
    const int row0 = blockIdx.x * 128;
    const float4* sW4 = (const float4*)sW;

    float4 pre[4];
    #pragma unroll
    for (int p = 0; p < 4; ++p) {
        int rowL = (tid >> 3) + 32 * p;
        int gr = row0 + rowL; if (gr >= N_NODES) gr = N_NODES - 1;
        pre[p] = *(const float4*)(Xr + (size_t)gr * Kd + (tid & 7) * 4);
    }

    for (int t = tid; t < Kd * 16; t += 256)
        ((float4*)sW)[t] = ((const float4*)Wr)[t];

    float4 acc[4][2];
    #pragma unroll
    for (int j = 0; j < 4; ++j) {
        acc[j][0] = make_float4(0.f, 0.f, 0.f, 0.f);
        acc[j][1] = make_float4(0.f, 0.f, 0.f, 0.f);
    }

    for (int k0 = 0; k0 < Kd; k0 += 32) {
        #pragma unroll
        for (int p = 0; p < 4; ++p) {
            int rowL = (tid >> 3) + 32 * p;
            int kk = (tid & 7) * 4;
            sX[(kk + 0) * 132 + rowL] = pre[p].x;
            sX[(kk + 1) * 132 + rowL] = pre[p].y;
            sX[(kk + 2) * 132 + rowL] = pre[p].z;
            sX[(kk + 3) * 132 + rowL] = pre[p].w;
        }
        __syncthreads();

        if (k0 + 32 < Kd) {
            #pragma unroll
            for (int p = 0; p < 4; ++p) {
                int rowL = (tid >> 3) + 32 * p;
                int gr = row0 + rowL; if (gr >= N_NODES) gr = N_NODES - 1;
                pre[p] = *(const float4*)(Xr + (size_t)gr * Kd + k0 + 32 + (tid & 7) * 4);
            }
        }

        #pragma unroll
        for (int kk = 0; kk < 32; ++kk) {
            float4 x4 = *(const float4*)(sX + kk * 132 + 4 * g);
            float4 wa = sW4[(k0 + kk) * 16 + 2 * c];
            float4 wb = sW4[(k0 + kk) * 16 + 2 * c + 1];
            #pragma unroll
            for (int j = 0; j < 4; ++j) {
                float xj = (j == 0) ? x4.x : (j == 1) ? x4.y : (j == 2) ? x4.z : x4.w;
                acc[j][0].x += xj * wa.x; acc[j][0].y += xj * wa.y;
                acc[j][0].z += xj * wa.z; acc[j][0].w += xj * wa.w;
                acc[j][1].x += xj * wb.x; acc[j][1].y += xj * wb.y;
                acc[j][1].z += xj * wb.z; acc[j][1].w += xj * wb.w;
            }
        }
        __syncthreads();
    }

    #pragma unroll
    for (int j = 0; j < 4; ++j) {
        int rr = row0 + 4 * g + j;
        if (rr < N_NODES) {
            float4* op = (float4*)(out + (size_t)rr * 64 + 8 * c);
            op[0] = acc[j][0];
            op[1] = acc[j][1];
        }
    }
}

// -------- fused CSR aggregation (64 feats): one wave per dst row, lane = feat ----
// R1-optimal gather structure; pinned at the scattered-gather ceiling
// (~3.6TB/s TCC; 45% HBM + 47% VALU + 79% occ; 4 structural variants +-8%).
template<int GEMV>
__global__ void __launch_bounds__(256) agg64_fused(const int* __restrict__ rowptr_all,
                                                   const int* __restrict__ col_all,
                                                   const float* __restrict__ enormp_all,
                                                   const float* __restrict__ hpre_all,
                                                   const float* __restrict__ dinv_all,
                                                   const float* __restrict__ bias_all,
                                                   const float* __restrict__ w2_all,
                                                   float* __restrict__ hout_all,
                                                   float* __restrict__ hpre3_all,
                                                   int r_base) {
    int gid = blockIdx.x * 256 + threadIdx.x;
    int row = gid >> 6;
    int lane = gid & 63;
    if (row >= N_NODES) return;
    int ry = blockIdx.y;
    int rin = r_base + ry;
    const int* rowptr = rowptr_all + (size_t)ry * (N_NODES + 1);
    const int* col = col_all + (size_t)ry * E_EDGES;
    const float* enormp = enormp_all + (size_t)ry * E_EDGES;
    const float* hpre = hpre_all + (size_t)ry * N_NODES * 64;
    const float* bias = bias_all + (size_t)rin * 64;
    int r0 = rowptr[row], r1 = rowptr[row + 1];
    float acc = 0.0f;
    for (int base = r0; base < r1; base += 64) {
        int e = base + lane;
        int cv = 0; float ev = 0.0f;
        if (e < r1) { cv = col[e]; ev = enormp[e]; }
        int m = r1 - base; if (m > 64) m = 64;
        int j = 0;
        for (; j + 8 <= m; j += 8) {
            int   s0 = __shfl(cv, j, 64),     s1 = __shfl(cv, j + 1, 64);
            int   s2 = __shfl(cv, j + 2, 64), s3 = __shfl(cv, j + 3, 64);
            int   s4 = __shfl(cv, j + 4, 64), s5 = __shfl(cv, j + 5, 64);
            int   s6 = __shfl(cv, j + 6, 64), s7 = __shfl(cv, j + 7, 64);
            float c0 = __shfl(ev, j, 64),     c1 = __shfl(ev, j + 1, 64);
            float c2 = __shfl(ev, j + 2, 64), c3 = __shfl(ev, j + 3, 64);
            float c4 = __shfl(ev, j + 4, 64), c5 = __shfl(ev, j + 5, 64);
            float c6 = __shfl(ev, j + 6, 64), c7 = __shfl(ev, j + 7, 64);
            float v0 = hpre[(size_t)s0 * 64 + lane];
            float v1 = hpre[(size_t)s1 * 64 + lane];
            float v2 = hpre[(size_t)s2 * 64 + lane];
            float v3 = hpre[(size_t)s3 * 64 + lane];
            float v4 = hpre[(size_t)s4 * 64 + lane];
            float v5 = hpre[(size_t)s5 * 64 + lane];
            float v6 = hpre[(size_t)s6 * 64 + lane];
            float v7 = hpre[(size_t)s7 * 64 + lane];
            acc += c0 * v0; acc += c1 * v1; acc += c2 * v2; acc += c3 * v3;
            acc += c4 * v4; acc += c5 * v5; acc += c6 * v6; acc += c7 * v7;
        }
        for (; j + 4 <= m; j += 4) {
            int   s0 = __shfl(cv, j, 64),     s1 = __shfl(cv, j + 1, 64);
            int   s2 = __shfl(cv, j + 2, 64), s3 = __shfl(cv, j + 3, 64);
            float c0 = __shfl(ev, j, 64),     c1 = __shfl(ev, j + 1, 64);
            float c2 = __shfl(ev, j + 2, 64), c3 = __shfl(ev, j + 3, 64);
            float v0 = hpre[(size_t)s0 * 64 + lane];
            float v1 = hpre[(size_t)s1 * 64 + lane];
            float v2 = hpre[(size_t)s2 * 64 + lane];
            float v3 = hpre[(size_t)s3 * 64 + lane];
            acc += c0 * v0; acc += c1 * v1; acc += c2 * v2; acc += c3 * v3;
        }
        for (; j < m; ++j) {
            int s = __shfl(cv, j, 64);
            float coef = __shfl(ev, j, 64);
            acc += coef * hpre[(size_t)s * 64 + lane];
        }
    }
    float dv = dinv_all[(size_t)ry * N_NODES + row];
    float val = tanhf(acc + dv * dv * hpre[(size_t)row * 64 + lane] + bias[lane]);
    hout_all[(size_t)ry * N_NODES * 64 + (size_t)row * 64 + lane] = val;
    if (GEMV) {
        float v = val * w2_all[(size_t)rin * 64 + lane];
        #pragma unroll
        for (int off = 32; off > 0; off >>= 1) v += __shfl_down(v, off, 64);
        if (lane == 0) hpre3_all[(size_t)ry * N_NODES + row] = v;
    }
}

// -------- fused CSR aggregation (1 feat): one thread per dst row --------
__global__ void agg1_fused(const int* __restrict__ rowptr_all, const int* __restrict__ col_all,
                           const float* __restrict__ enormp_all, const float* __restrict__ hpre3_all,
                           const float* __restrict__ dinv_all, const float* __restrict__ b2_all,
                           float* __restrict__ h3_all, int r_base) {
    int i = blockIdx.x * blockDim.x + threadIdx.x;
    if (i >= N_NODES) return;
    int ry = blockIdx.y;
    const int* rowptr = rowptr_all + (size_t)ry * (N_NODES + 1);
    const int* col = col_all + (size_t)ry * E_EDGES;
    const float* enormp = enormp_all + (size_t)ry * E_EDGES;
    const float* hpre3 = hpre3_all + (size_t)ry * N_NODES;
    float acc = 0.0f;
    int r1 = rowptr[i + 1];
    for (int e = rowptr[i]; e < r1; ++e) acc += enormp[e] * hpre3[col[e]];
    float dv = dinv_all[(size_t)ry * N_NODES + i];
    h3_all[(size_t)ry * N_NODES + i] =
        tanhf(acc + dv * dv * hpre3[i] + b2_all[r_base + ry]);
}

// ---------------- group compaction: deterministic counting sort ----------------
__global__ void __launch_bounds__(256) grp_hist(const int* __restrict__ group,
                                                int* __restrict__ bcnt, int n) {
    __shared__ int lh[NG];
    int b = blockIdx.x, t = threadIdx.x;
    if (t < NG) lh[t] = 0;
    __syncthreads();
    int i = b * 256 + t;
    if (i < n) atomicAdd(&lh[group[i]], 1);
    __syncthreads();
    if (t < NG) bcnt[t * NBLK + b] = lh[t];
}

__global__ void __launch_bounds__(512) grp_scan(const int* __restrict__ bcnt,
                                                int* __restrict__ boff,
                                                int* __restrict__ cnt) {
    __shared__ int s[512];
    int g = blockIdx.x, t = threadIdx.x;
    int orig = t < NBLK ? bcnt[g * NBLK + t] : 0;
    s[t] = orig;
    __syncthreads();
    for (int o = 1; o < 512; o <<= 1) {
        int v = t >= o ? s[t - o] : 0;
        __syncthreads();
        s[t] += v;
        __syncthreads();
    }
    if (t < NBLK) boff[g * NBLK + t] = s[t] - orig;
    if (t == 511) cnt[g] = s[NBLK - 1] > CAP ? CAP : s[NBLK - 1];
}

__global__ void __launch_bounds__(256) grp_fill(const int* __restrict__ group,
                                                const int* __restrict__ boff,
                                                int* __restrict__ lists, int n) {
    __shared__ int lcur[NG];
    int b = blockIdx.x, t = threadIdx.x;
    if (t < NG) lcur[t] = 0;
    __syncthreads();
    int i = b * 256 + t;
    if (i < n) {
        int g = group[i];
        int p = atomicAdd(&lcur[g], 1);
        int pos = boff[g * NBLK + b] + p;
        if (pos < CAP) lists[g * CAP + pos] = i;
    }
}

// ---------------- fused per-group top-K + sort-pool + conv1 + maxpool + conv2 ----
__device__ __forceinline__ unsigned int fkey(float v) {
    unsigned int b = __float_as_uint(v);
    return (b & 0x80000000u) ? ~b : (b | 0x80000000u);
}

__global__ void __launch_bounds__(256) topk_pool(const int* __restrict__ cnt,
                                                 const int* __restrict__ lists,
                                                 const float* __restrict__ h1_all,
                                                 const float* __restrict__ h2_all,
                                                 const float* __restrict__ h3_all,
                                                 const float* __restrict__ c1w,
                                                 const float* __restrict__ c1b,
                                                 const float* __restrict__ c2w,
                                                 const float* __restrict__ c2b,
                                                 float* __restrict__ out3,
                                                 int r_base) {
    __shared__ unsigned long long wmax[4];
    __shared__ unsigned long long winner;
    __shared__ int s_top[KTOP];
    __shared__ float sfeat[KTOP * DFLAT];
    __shared__ float sy[NC1 * KTOP];
    __shared__ float sm[NC1 * (KTOP / 2)];
    int g = blockIdx.x;
    int ry = blockIdx.y;
    const float* h1 = h1_all + (size_t)ry * N_NODES * 64;
    const float* h2 = h2_all + (size_t)ry * N_NODES * 64;
    const float* h3 = h3_all + (size_t)ry * N_NODES;
    float* o = out3 + (size_t)(r_base + ry) * NOUT;
    int tid = threadIdx.x;
    int lane = tid & 63, wid = tid >> 6;
    int c = cnt[g];
    if (c > CAP) c = CAP;

    unsigned long long key[SLOTS];
    #pragma unroll
    for (int s = 0; s < SLOTS; ++s) {
        int e = s * 256 + tid;
        if (e < c) {
            int node = lists[g * CAP + e];
            key[s] = ((unsigned long long)fkey(h3[node]) << 32) | (unsigned int)(~node);
        } else {
            key[s] = 0ull;
        }
    }

    for (int k = 0; k < KTOP; ++k) {
        unsigned long long best = 0ull;
        #pragma unroll
        for (int s = 0; s < SLOTS; ++s) best = key[s] > best ? key[s] : best;
        #pragma unroll
        for (int off = 32; off > 0; off >>= 1) {
            unsigned long long oo = __shfl_down(best, off, 64);
            best = oo > best ? oo : best;
        }
        if (lane == 0) wmax[wid] = best;
        __syncthreads();
        if (tid == 0) {
            unsigned long long b = wmax[0];
            for (int w = 1; w < 4; ++w) b = wmax[w] > b ? wmax[w] : b;
            winner = b;
            s_top[k] = ~(int)(unsigned int)b;
        }
        __syncthreads();
        unsigned long long w = winner;
        #pragma unroll
        for (int s = 0; s < SLOTS; ++s) if (key[s] == w) key[s] = 0ull;
        __syncthreads();
    }

    for (int t = tid; t < KTOP * DFLAT; t += blockDim.x) {
        int k = t / DFLAT, d = t - k * DFLAT;
        int node = s_top[k];
        float v;
        if (d < 64)        v = h1[(size_t)node * 64 + d];
        else if (d < 128)  v = h2[(size_t)node * 64 + (d - 64)];
        else               v = h3[node];
        sfeat[t] = v;
    }
    __syncthreads();

    for (int t = tid; t < NC1 * KTOP; t += blockDim.x) {
        int cc = t / KTOP, k = t - cc * KTOP;
        float acc = c1b[cc];
        const float* w = c1w + cc * DFLAT;
        const float* f = sfeat + k * DFLAT;
        for (int d = 0; d < DFLAT; ++d) acc += f[d] * w[d];
        sy[cc * KTOP + k] = fmaxf(acc, 0.0f);
    }
    __syncthreads();

    for (int t = tid; t < NC1 * (KTOP / 2); t += blockDim.x) {
        int cc = t / (KTOP / 2), j = t - cc * (KTOP / 2);
        sm[t] = fmaxf(sy[cc * KTOP + 2 * j], sy[cc * KTOP + 2 * j + 1]);
    }
    __syncthreads();

    for (int t = tid; t < NC2 * TOUT; t += blockDim.x) {
        int c2 = t / TOUT, tt = t - c2 * TOUT;
        float acc = c2b[c2];
        for (int c1i = 0; c1i < NC1; ++c1i) {
            const float* w = c2w + (c2 * NC1 + c1i) * KSZ;
            const float* m = sm + c1i * (KTOP / 2) + tt;
            for (int s = 0; s < KSZ; ++s) acc += m[s] * w[s];
        }
        o[g * NC2 * TOUT + t] = fmaxf(acc, 0.0f);
    }
}

// final sum over relations in fixed order r0,r1,r2 -> bitwise identical to the
// old sequential "+=" accumulation ((0+v0)+v1)+v2.
__global__ void reduce_out(const float* __restrict__ out3, float* __restrict__ out, int n) {
    int i = blockIdx.x * blockDim.x + threadIdx.x;
    if (i >= n) return;
    float s = 0.0f;
    s += out3[i];
    s += out3[(size_t)n + i];
    s += out3[(size_t)2 * n + i];
    out[i] = s;
}

// ---------------- host ----------------
extern "C" void kernel_launch(void* const* d_in, const int* in_sizes, int n_in,
                              void* d_out, int out_size, void* d_ws, size_t ws_size,
                              hipStream_t stream) {
    const float* x       = (const float*)d_in[0];
    const int*   eidx    = (const int*)d_in[1];    // [R,2,E]
    const float* ew      = (const float*)d_in[2];  // [R,E]
    const int*   group   = (const int*)d_in[3];    // [N]
    const float* W0      = (const float*)d_in[4];  // [R,128,64]
    const float* b0      = (const float*)d_in[5];
    const float* W1      = (const float*)d_in[6];  // [R,64,64]
    const float* b1      = (const float*)d_in[7];
    const float* W2      = (const float*)d_in[8];  // [R,64,1]
    const float* b2      = (const float*)d_in[9];
    const float* c1w     = (const float*)d_in[10];
    const float* c1b     = (const float*)d_in[11];
    const float* c2w     = (const float*)d_in[12];
    const float* c2b     = (const float*)d_in[13];
    float* out = (float*)d_out;

    char* ws = (char*)d_ws;

    float *dinv, *ewp, *hpre, *h1, *h2, *hpre3, *h3, *out3;
    int *rowptr, *col, *cnt, *lists, *bcnt, *boff, *chist, *btot, *bb;
    int4* staged;

    size_t off = 0;
    auto layout = [&](char* base, int ns) -> size_t {
        off = 0;
        auto A = [&](size_t bytes) -> char* {
            char* p = base + off;
            off = (off + bytes + 255) & ~(size_t)255;
            return p;
        };
        dinv    = (float*)A((size_t)ns * N_NODES * 4);
        rowptr  = (int*)  A((size_t)ns * (N_NODES + 1) * 4);
        col     = (int*)  A((size_t)ns * E_EDGES * 4);
        ewp     = (float*)A((size_t)ns * E_EDGES * 4);   // becomes enormp in place
        staged  = (int4*) A((size_t)ns * E_EDGES * 16);  // aliases hpre
        hpre    = (float*)staged;
        h1      = (float*)A((size_t)ns * N_NODES * 64 * 4);  // also scatter3 fallback scratch
        h2      = (float*)A((size_t)ns * N_NODES * 64 * 4);
        hpre3   = (float*)A((size_t)ns * N_NODES * 4);
        h3      = (float*)A((size_t)ns * N_NODES * 4);
        out3    = (float*)A((size_t)3 * NOUT * 4);       // always 3 (indexed by real r)
        cnt     = (int*)  A((size_t)NG * 4);
        lists   = (int*)  A((size_t)NG * CAP * 4);
        bcnt    = (int*)  A((size_t)NG * NBLK * 4);
        boff    = (int*)  A((size_t)NG * NBLK * 4);
        chist   = (int*)  A((size_t)ns * NB * NCHUNK * 4);  // scanned in place -> chunkoff
        btot    = (int*)  A((size_t)ns * (NB + 1) * 4);
        bb      = (int*)  A((size_t)ns * (NB + 1) * 4);
        return off;
    };

    int nslots = 3;
    size_t need = layout(ws, 3);
    if (need > ws_size) { nslots = 2; need = layout(ws, 2); }
    if (need > ws_size) { nslots = 1; need = layout(ws, 1); }

    const int B  = 256;
    const int gN = (N_NODES + B - 1) / B;          // 391
    const int gW = (N_NODES * 64 + B - 1) / B;     // 25000
    const int gG = (N_NODES + 127) / 128;          // 782
    const dim3 blk(B);

    // group compaction: relation-independent, once per launch
    grp_hist<<<NBLK, B, 0, stream>>>(group, bcnt, N_NODES);
    grp_scan<<<NG, 512, 0, stream>>>(bcnt, boff, cnt);
    grp_fill<<<NBLK, B, 0, stream>>>(group, boff, lists, N_NODES);

    for (int r0 = 0; r0 < R_REL; r0 += nslots) {
        int ny = R_REL - r0; if (ny > nslots) ny = nslots;

        // ---- binned permutation CSR build (sort + dinv fused into scatter3) ----
        bin_hist   <<<dim3(NCHUNK, ny), blk, 0, stream>>>(eidx, chist, r0);
        bin_scan   <<<dim3(NB, ny), dim3(512), 0, stream>>>(chist, btot);
        bucket_scan<<<dim3(ny), dim3(512), 0, stream>>>(btot, bb);
        bin_stage  <<<dim3(NCHUNK, ny), blk, 0, stream>>>(eidx, ew, chist, bb,
                                                          staged, r0);
        bin_scatter3<<<dim3(NB, ny), blk, 0, stream>>>(staged, bb, rowptr,
                                                       col, ewp, dinv, (int*)h1);
        enorm_csr  <<<dim3(gN, ny), blk, 0, stream>>>(rowptr, col, ewp, dinv);

        // layer 1 (hpre overwrites the now-dead staged)
        gemm_v4<128><<<dim3(gG, ny), blk, 0, stream>>>(x, 0, W0, 128 * 64, hpre, r0);
        agg64_fused<0><<<dim3(gW, ny), blk, 0, stream>>>(rowptr, col, ewp, hpre,
                                                         dinv, b0, nullptr, h1,
                                                         nullptr, r0);
        // layer 2 (+ fused gemv -> hpre3)
        gemm_v4<64><<<dim3(gG, ny), blk, 0, stream>>>(h1, (size_t)N_NODES * 64, W1,
                                                      64 * 64, hpre, r0);
        agg64_fused<1><<<dim3(gW, ny), blk, 0, stream>>>(rowptr, col, ewp, hpre,
                                                         dinv, b1, W2, h2, hpre3, r0);
        // layer 3
        agg1_fused<<<dim3(gN, ny), blk, 0, stream>>>(rowptr, col, ewp, hpre3,
                                                     dinv, b2, h3, r0);
        // fused sort pooling + convs (writes out3 slice for real relation r0+ry)
        topk_pool<<<dim3(NG, ny), blk, 0, stream>>>(cnt, lists, h1, h2, h3,
                                                    c1w, c1b, c2w, c2b, out3, r0);
    }

    reduce_out<<<(NOUT + B - 1) / B, B, 0, stream>>>(out3, out, NOUT);
}